// Round 14
// baseline (701.746 us; speedup 1.0000x reference)
//
#include <hip/hip_runtime.h>

typedef __bf16 bf16x8 __attribute__((ext_vector_type(8)));
typedef __bf16 bf16x4 __attribute__((ext_vector_type(4)));
typedef float f32x4 __attribute__((ext_vector_type(4)));

constexpr int cN   = 20000;   // nodes total
constexpr int cG   = 200;     // graphs
constexpr int cNPG = 100;     // nodes per graph
constexpr int cE   = 160000;  // edges total
constexpr int cEPG = 800;     // edges per graph
constexpr int cHID = 256;
constexpr int cIN  = 21;
constexpr float cEPS   = 1e-5f;
constexpr float cSLOPE = 0.2f;
constexpr int cCH  = 32;      // csr chunks per graph
constexpr int cCHS = 25;      // edges per chunk

__device__ __forceinline__ float4 cvt4(bf16x4 v) {
    return make_float4((float)v.x, (float)v.y, (float)v.z, (float)v.w);
}

// async global->LDS, 16B per lane; lds dest must be wave-uniform base
__device__ __forceinline__ void gl_lds16(const __bf16* g, __bf16* l) {
    __builtin_amdgcn_global_load_lds(
        (const __attribute__((address_space(1))) void*)g,
        (__attribute__((address_space(3))) void*)l, 16, 0, 0);
}

// ---- layer-0: fsb/fdb = bf16(x@W+b), resb = bf16(x@Wres) ----
// block 0 also zeroes the BN accumulators (runs before layer-0 edge2)
__global__ __launch_bounds__(256) void k_in_gemm(
    const float* __restrict__ x,
    const float* __restrict__ Ws, const float* __restrict__ bs,
    const float* __restrict__ Wd, const float* __restrict__ bd,
    const float* __restrict__ Wr,
    __bf16* __restrict__ fsb, __bf16* __restrict__ fdb, __bf16* __restrict__ resb,
    float* __restrict__ bnz)
{
    __shared__ float xl[8 * cIN];
    int tid = threadIdx.x;
    if (blockIdx.x == 0) { bnz[tid] = 0.f; bnz[tid + 256] = 0.f; }
    int rb  = blockIdx.x * 8;
    if (tid < 8 * cIN) xl[tid] = x[(size_t)rb * cIN + tid];
    __syncthreads();
    int j = tid;
    float ws[cIN], wd[cIN], wr[cIN];
#pragma unroll
    for (int k = 0; k < cIN; ++k) {
        ws[k] = Ws[k * cHID + j];
        wd[k] = Wd[k * cHID + j];
        wr[k] = Wr[k * cHID + j];
    }
    float vbs = bs[j], vbd = bd[j];
    for (int r = 0; r < 8; ++r) {
        float as = vbs, ad = vbd, ar = 0.f;
#pragma unroll
        for (int k = 0; k < cIN; ++k) {
            float xv = xl[r * cIN + k];
            as += xv * ws[k];
            ad += xv * wd[k];
            ar += xv * wr[k];
        }
        size_t o = (size_t)(rb + r) * cHID + j;
        fsb[o] = (__bf16)as; fdb[o] = (__bf16)ad; resb[o] = (__bf16)ar;
    }
}

// ---- weight convert + transpose into per-layer Wcat[512][256] ----
// rows 0-255: Ws^T, rows 256-511: Wd^T
__global__ __launch_bounds__(256) void k_wcvt(
    const float* __restrict__ Ws_r, const float* __restrict__ Wd_r,
    __bf16* __restrict__ WT)
{
    int mat = blockIdx.y;
    int l = mat >> 1;
    const float* W = ((mat & 1) ? Wd_r : Ws_r) + (size_t)l * cHID * cHID;
    __bf16* T = WT + (size_t)l * 512 * cHID + (size_t)(mat & 1) * cHID * cHID;
    int k = blockIdx.x, n = threadIdx.x;
    T[(size_t)n * cHID + k] = (__bf16)W[(size_t)k * cHID + n];
}

// ---- layers 1-3: 128x128-tile LDS-staged MFMA GEMM (m97 pattern) ----
// C[20000,512] = hb[20000,256] @ Wcat^T; cols<256 -> fsb, cols>=256 -> fdb
// block (0,0) zeroes BN accumulators for this layer (runs before edge2)
__global__ __launch_bounds__(256) void k_gemm_mfma(
    const __bf16* __restrict__ hb, const __bf16* __restrict__ Wcat,
    const float* __restrict__ bs, const float* __restrict__ bd,
    __bf16* __restrict__ fsb, __bf16* __restrict__ fdb,
    float* __restrict__ bnz)
{
    __shared__ __bf16 lA[128 * 32];   // 8 KB
    __shared__ __bf16 lB[128 * 32];   // 8 KB
    int tid = threadIdx.x, lane = tid & 63, w = tid >> 6;
    if (blockIdx.x == 0 && blockIdx.y == 0) { bnz[tid] = 0.f; bnz[tid + 256] = 0.f; }
    int wr = w >> 1, wc = w & 1;
    int rc = lane & 15, kg = lane >> 4;
    int m0  = blockIdx.x * 128;
    int bn0 = blockIdx.y * 128;

    f32x4 acc[4][4];
#pragma unroll
    for (int m = 0; m < 4; ++m)
#pragma unroll
        for (int n = 0; n < 4; ++n)
            acc[m][n] = (f32x4){0.f, 0.f, 0.f, 0.f};

#pragma unroll 1
    for (int ks = 0; ks < 8; ++ks) {
        int k0 = ks * 32;
        // stage A[128][32] and B[128][32]; 512 chunks of 16B each
#pragma unroll
        for (int j = 0; j < 2; ++j) {
            int c   = j * 256 + tid;          // this lane's chunk
            int row = c >> 2, ci = c & 3;
            __bf16* dA = &lA[(size_t)(j * 256 + w * 64) * 8];  // wave-uniform
            __bf16* dB = &lB[(size_t)(j * 256 + w * 64) * 8];
            gl_lds16(hb   + (size_t)(m0  + row) * cHID + k0 + ci * 8, dA);
            gl_lds16(Wcat + (size_t)(bn0 + row) * cHID + k0 + ci * 8, dB);
        }
        __syncthreads();

        bf16x8 a[4], b[4];
#pragma unroll
        for (int m = 0; m < 4; ++m)
            a[m] = *(const bf16x8*)&lA[(wr * 64 + m * 16 + rc) * 32 + kg * 8];
#pragma unroll
        for (int n = 0; n < 4; ++n)
            b[n] = *(const bf16x8*)&lB[(wc * 64 + n * 16 + rc) * 32 + kg * 8];
#pragma unroll
        for (int m = 0; m < 4; ++m)
#pragma unroll
            for (int n = 0; n < 4; ++n)
                acc[m][n] = __builtin_amdgcn_mfma_f32_16x16x32_bf16(a[m], b[n], acc[m][n], 0, 0, 0);
        __syncthreads();
    }

#pragma unroll
    for (int m = 0; m < 4; ++m) {
        int rbase = m0 + wr * 64 + m * 16 + kg * 4;
#pragma unroll
        for (int n = 0; n < 4; ++n) {
            int col = bn0 + wc * 64 + n * 16 + rc;
            bool isS = col < cHID;
            int  cc  = isS ? col : col - cHID;
            float bias = isS ? bs[cc] : bd[cc];
            __bf16* dst = isS ? fsb : fdb;
#pragma unroll
            for (int i = 0; i < 4; ++i) {
                int r = rbase + i;
                if (r < cN)
                    dst[(size_t)r * cHID + cc] = (__bf16)(acc[m][n][i] + bias);
            }
        }
    }
}

// ---- CSR build by dst: chunked stable counting sort (deterministic) ----
__global__ __launch_bounds__(256) void k_csr(
    const int* __restrict__ dst, int* __restrict__ csr,
    int* __restrict__ off, int* __restrict__ deg)
{
    __shared__ int dstl[cEPG];
    __shared__ int cnt[cCH * 128];     // [chunk][node] (128-padded rows)
    __shared__ int offl[cNPG];
    __shared__ int tot[128];
    int g = blockIdx.x, tid = threadIdx.x;
    int nb = g * cNPG, eb = g * cEPG;

    for (int i = tid; i < cEPG; i += 256) dstl[i] = dst[eb + i] - nb;
    for (int i = tid; i < cCH * 128; i += 256) cnt[i] = 0;
    __syncthreads();

    for (int i = tid; i < cEPG; i += 256)
        atomicAdd(&cnt[(i / cCHS) * 128 + dstl[i]], 1);
    __syncthreads();

    int mytot = 0;
    if (tid < cNPG) {
        int run = 0;
        for (int c = 0; c < cCH; ++c) {
            int t = cnt[c * 128 + tid];
            cnt[c * 128 + tid] = run;
            run += t;
        }
        mytot = run;
    }
    if (tid < 128) tot[tid] = (tid < cNPG) ? mytot : 0;
    __syncthreads();
    for (int ofs = 1; ofs < 128; ofs <<= 1) {
        int t = 0;
        if (tid < 128 && tid >= ofs) t = tot[tid - ofs];
        __syncthreads();
        if (tid < 128) tot[tid] += t;
        __syncthreads();
    }
    if (tid < cNPG) {
        int excl = tot[tid] - mytot;
        offl[tid] = excl;
        off[nb + tid] = eb + excl;
        deg[nb + tid] = mytot;
    }
    __syncthreads();

    if (tid < cCH) {
        for (int j = 0; j < cCHS; ++j) {
            int i = tid * cCHS + j;
            int n = dstl[i];
            int k = cnt[tid * 128 + n]++;
            csr[eb + offl[n] + k] = eb + i;
        }
    }
}

// ---- fused edge stage: wave/node single pass + fused BN column stats ----
// blockIdx swizzle: g = bid % 200 keeps each graph's blocks on one XCD
__global__ __launch_bounds__(256) void k_edge2(
    const __bf16* __restrict__ fsb, const __bf16* __restrict__ fdb,
    const __bf16* __restrict__ resb, const float* __restrict__ avec,
    const int* __restrict__ csr, const int* __restrict__ off,
    const int* __restrict__ deg, const int* __restrict__ src,
    float* __restrict__ hpre, float* __restrict__ attn_out,
    float* __restrict__ spill, float* __restrict__ gsum,
    float* __restrict__ gssq, float* __restrict__ fcl)
{
    __shared__ int   sidx[4][64];
    __shared__ int   eidx[4][64];
    __shared__ float exbuf[4][64];
    __shared__ float hblk[4][256];
    int tid = threadIdx.x, lane = tid & 63, w = tid >> 6;
    int bid = blockIdx.x;
    if (bid < cG)                              // zero this layer's featcat row
        fcl[(size_t)bid * (4 * cHID) + tid] = 0.f;
    int g   = bid % cG;                         // 5000 blocks = 200 graphs x 25
    int nid = g * cNPG + (bid / cG) * 4 + w;
    int dg = deg[nid], base = off[nid];

    // prefetch edge + src indices (lane-parallel, within-wave LDS)
    for (int i = lane; i < dg && i < 64; i += 64) {
        int e = csr[base + i];
        eidx[w][i] = e;
        sidx[w][i] = src[e];
    }

    float4 a4  = *(const float4*)(avec + lane * 4);
    float4 fd4 = cvt4(*(const bf16x4*)(fdb + (size_t)nid * cHID + lane * 4));
    float4 r4  = cvt4(*(const bf16x4*)(resb + (size_t)nid * cHID + lane * 4));

    // single pass: score -> exp -> accumulate (fs slice reused in registers)
    float den = 0.f;
    float4 acc = {0.f, 0.f, 0.f, 0.f};
    for (int i = 0; i < dg; ++i) {
        int s = (i < 64) ? sidx[w][i] : src[csr[base + i]];
        float4 f4 = cvt4(*(const bf16x4*)(fsb + (size_t)s * cHID + lane * 4));
        float v0 = f4.x + fd4.x, v1 = f4.y + fd4.y;
        float v2 = f4.z + fd4.z, v3 = f4.w + fd4.w;
        v0 = v0 > 0.f ? v0 : cSLOPE * v0;
        v1 = v1 > 0.f ? v1 : cSLOPE * v1;
        v2 = v2 > 0.f ? v2 : cSLOPE * v2;
        v3 = v3 > 0.f ? v3 : cSLOPE * v3;
        float part = v0 * a4.x + v1 * a4.y + v2 * a4.z + v3 * a4.w;
#pragma unroll
        for (int o = 32; o; o >>= 1) part += __shfl_xor(part, o);
        float ex = __expf(part);                // all lanes hold full score
        den += ex;
        acc.x += ex * f4.x; acc.y += ex * f4.y;
        acc.z += ex * f4.z; acc.w += ex * f4.w;
        if (lane == 0) {
            if (i < 64) exbuf[w][i] = ex;
            else        spill[csr[base + i]] = ex;
        }
    }
    float inv = (dg > 0) ? 1.f / den : 0.f;     // den identical on all lanes

    // attn output
    for (int i = lane; i < dg; i += 64) {
        float ex = (i < 64) ? exbuf[w][i] : spill[csr[base + i]];
        int e    = (i < 64) ? eidx[w][i]  : csr[base + i];
        attn_out[(size_t)e * 4] = ex * inv;
    }

    // normalize + residual; stash row in LDS for the stats reduce
    float4 o4 = {acc.x * inv + r4.x, acc.y * inv + r4.y,
                 acc.z * inv + r4.z, acc.w * inv + r4.w};
    *(float4*)(hpre + (size_t)nid * cHID + lane * 4) = o4;
    *(float4*)&hblk[w][lane * 4] = o4;
    __syncthreads();

    // fused BN stats: per-dim sum / sumsq over this block's 4 nodes
    float v0 = hblk[0][tid], v1 = hblk[1][tid], v2 = hblk[2][tid], v3 = hblk[3][tid];
    atomicAdd(&gsum[tid], v0 + v1 + v2 + v3);
    atomicAdd(&gssq[tid], v0 * v0 + v1 * v1 + v2 * v2 + v3 * v3);
}

// ---- BN apply + ReLU + graph-mean (atomic): grid (200,4); bf16 h only ----
__global__ __launch_bounds__(256) void k_bn_apply(
    const float* __restrict__ hpre,
    const float* __restrict__ gsum, const float* __restrict__ gssq,
    const float* __restrict__ gamma, const float* __restrict__ beta,
    __bf16* __restrict__ hb, float* __restrict__ featcat_l)
{
    int j = threadIdx.x, g = blockIdx.x, q = blockIdx.y;
    float mu  = gsum[j] * (1.f / cN);
    float var = gssq[j] * (1.f / cN) - mu * mu;
    float sc  = gamma[j] * rsqrtf(var + cEPS);
    float sh  = beta[j] - mu * sc;
    float fsum = 0.f;
    int r0 = g * cNPG + q * 25;
    for (int r = 0; r < 25; ++r) {
        size_t i = (size_t)(r0 + r) * cHID + j;
        float v = hpre[i] * sc + sh;
        v = v > 0.f ? v : 0.f;
        hb[i] = (__bf16)v;
        fsum += v;
    }
    atomicAdd(&featcat_l[(size_t)g * (4 * cHID) + j], fsum * (1.f / cNPG));
}

// ---- head: feat2 = featcat @ fc1_W + fc1_b ----
__global__ __launch_bounds__(256) void k_fc1(
    const float* __restrict__ featcat, const float* __restrict__ W,
    const float* __restrict__ b, float* __restrict__ out)
{
    __shared__ float row[4 * cHID];
    int g = blockIdx.x, j = threadIdx.x;
    for (int i = j; i < 4 * cHID; i += 256) row[i] = featcat[(size_t)g * (4 * cHID) + i];
    __syncthreads();
    float acc = b[j];
    for (int k = 0; k < 4 * cHID; ++k) acc += row[k] * W[(size_t)k * cHID + j];
    out[(size_t)g * cHID + j] = acc;
}

// ---- head BN (over 200 rows) + ReLU, in place ----
__global__ __launch_bounds__(256) void k_fc_bn(
    float* __restrict__ f2, const float* __restrict__ gamma, const float* __restrict__ beta)
{
    int j = threadIdx.x;
    float s = 0.f, q = 0.f;
    for (int r = 0; r < cG; ++r) { float v = f2[(size_t)r * cHID + j]; s += v; q += v * v; }
    float mu  = s * (1.f / cG);
    float var = q * (1.f / cG) - mu * mu;
    float sc  = gamma[j] * rsqrtf(var + cEPS);
    float sh  = beta[j] - mu * sc;
    for (int r = 0; r < cG; ++r) {
        float v = f2[(size_t)r * cHID + j] * sc + sh;
        f2[(size_t)r * cHID + j] = v > 0.f ? v : 0.f;
    }
}

// ---- head: out[r*5+o] = feat2[r] . fc2_W[:,o] + fc2_b[o] ----
__global__ __launch_bounds__(256) void k_fc2(
    const float* __restrict__ f2, const float* __restrict__ W,
    const float* __restrict__ b, float* __restrict__ out)
{
    int t = blockIdx.x * 256 + threadIdx.x;
    if (t >= cG * 5) return;
    int r = t / 5, o = t % 5;
    float acc = b[o];
    for (int k = 0; k < cHID; ++k) acc += f2[(size_t)r * cHID + k] * W[k * 5 + o];
    out[t] = acc;
}

extern "C" void kernel_launch(void* const* d_in, const int* in_sizes, int n_in,
                              void* d_out, int out_size, void* d_ws, size_t ws_size,
                              hipStream_t stream)
{
    (void)in_sizes; (void)n_in; (void)out_size; (void)ws_size;
    const float* x     = (const float*)d_in[0];
    const float* Ws0   = (const float*)d_in[1];
    const float* bs0   = (const float*)d_in[2];
    const float* Wd0   = (const float*)d_in[3];
    const float* bd0   = (const float*)d_in[4];
    const float* a0    = (const float*)d_in[5];
    const float* Wres0 = (const float*)d_in[6];
    const float* g0    = (const float*)d_in[7];
    const float* be0   = (const float*)d_in[8];
    const float* Ws_r  = (const float*)d_in[9];
    const float* bs_r  = (const float*)d_in[10];
    const float* Wd_r  = (const float*)d_in[11];
    const float* bd_r  = (const float*)d_in[12];
    const float* a_r   = (const float*)d_in[13];
    const float* g_r   = (const float*)d_in[14];
    const float* be_r  = (const float*)d_in[15];
    const float* fc1_W = (const float*)d_in[16];
    const float* fc1_b = (const float*)d_in[17];
    const float* gfc   = (const float*)d_in[18];
    const float* bfc   = (const float*)d_in[19];
    const float* fc2_W = (const float*)d_in[20];
    const float* fc2_b = (const float*)d_in[21];
    const int*   src   = (const int*)d_in[22];
    const int*   dst   = (const int*)d_in[23];
    float* out = (float*)d_out;

    char* p = (char*)d_ws;
    float* hpre    = (float*)p; p += (size_t)cN * cHID * 4;
    float* featcat = (float*)p; p += (size_t)cG * 4 * cHID * 4;
    float* feat2   = (float*)p; p += (size_t)cG * cHID * 4;
    float* gsum    = (float*)p; p += cHID * 4;
    float* gssq    = (float*)p; p += cHID * 4;
    float* spill   = (float*)p; p += (size_t)cE * 4;
    int*   csr     = (int*)p;   p += (size_t)cE * 4;
    int*   offv    = (int*)p;   p += (size_t)cN * 4;
    int*   degv    = (int*)p;   p += (size_t)cN * 4;
    __bf16* hb     = (__bf16*)p; p += (size_t)cN * cHID * 2;
    __bf16* resb0  = (__bf16*)p; p += (size_t)cN * cHID * 2;
    __bf16* fsb    = (__bf16*)p; p += (size_t)cN * cHID * 2;
    __bf16* fdb    = (__bf16*)p; p += (size_t)cN * cHID * 2;
    __bf16* WT     = (__bf16*)p; p += (size_t)3 * 512 * cHID * 2;

    // one-time setup: weight convert/transpose + CSR by dst
    k_wcvt<<<dim3(cHID, 6), 256, 0, stream>>>(Ws_r, Wd_r, WT);
    k_csr<<<cG, 256, 0, stream>>>(dst, csr, offv, degv);

    // layer 0 projections (f32 math, bf16 emit); zeroes BN accumulators
    k_in_gemm<<<cN / 8, 256, 0, stream>>>(x, Ws0, bs0, Wd0, bd0, Wres0,
                                          fsb, fdb, resb0, gsum);

    for (int l = 0; l < 4; ++l) {
        if (l > 0) {
            k_gemm_mfma<<<dim3(157, 4), 256, 0, stream>>>(
                hb,
                WT + (size_t)(l - 1) * 512 * cHID,
                bs_r + (size_t)(l - 1) * cHID, bd_r + (size_t)(l - 1) * cHID,
                fsb, fdb, gsum);
        }
        const float* ap = (l == 0) ? a0 : a_r + (size_t)(l - 1) * cHID;
        const __bf16* rb = (l == 0) ? resb0 : hb;
        float* fcl = featcat + (size_t)l * cHID;
        k_edge2<<<cN / 4, 256, 0, stream>>>(fsb, fdb, rb, ap, csr, offv, degv, src,
                                            hpre, out + 1000 + l, spill,
                                            gsum, gssq, fcl);
        const float* gm = (l == 0) ? g0  : g_r  + (size_t)(l - 1) * cHID;
        const float* bt = (l == 0) ? be0 : be_r + (size_t)(l - 1) * cHID;
        k_bn_apply<<<dim3(cG, 4), 256, 0, stream>>>(hpre, gsum, gssq, gm, bt, hb, fcl);
    }

    k_fc1<<<cG, 256, 0, stream>>>(featcat, fc1_W, fc1_b, feat2);
    k_fc_bn<<<1, 256, 0, stream>>>(feat2, gfc, bfc);
    k_fc2<<<4, 256, 0, stream>>>(feat2, fc2_W, fc2_b, out);
}

// Round 15
// 310.456 us; speedup vs baseline: 2.2604x; 2.2604x over previous
//
#include <hip/hip_runtime.h>

typedef __bf16 bf16x8 __attribute__((ext_vector_type(8)));
typedef __bf16 bf16x4 __attribute__((ext_vector_type(4)));
typedef float f32x4 __attribute__((ext_vector_type(4)));

constexpr int cN   = 20000;   // nodes total
constexpr int cG   = 200;     // graphs
constexpr int cNPG = 100;     // nodes per graph
constexpr int cE   = 160000;  // edges total
constexpr int cEPG = 800;     // edges per graph
constexpr int cHID = 256;
constexpr int cIN  = 21;
constexpr float cEPS   = 1e-5f;
constexpr float cSLOPE = 0.2f;
constexpr int cCH  = 32;      // csr chunks per graph
constexpr int cCHS = 25;      // edges per chunk
constexpr int cPART = 32;     // BN-stat partial slots (contention 5000 -> 156)

__device__ __forceinline__ float4 cvt4(bf16x4 v) {
    return make_float4((float)v.x, (float)v.y, (float)v.z, (float)v.w);
}

// async global->LDS, 16B per lane; lds dest must be wave-uniform base
__device__ __forceinline__ void gl_lds16(const __bf16* g, __bf16* l) {
    __builtin_amdgcn_global_load_lds(
        (const __attribute__((address_space(1))) void*)g,
        (__attribute__((address_space(3))) void*)l, 16, 0, 0);
}

// ---- layer-0: fsb/fdb = bf16(x@W+b), resb = bf16(x@Wres) ----
// block 0 zeroes the 2*cPART*256 BN partial accumulators
__global__ __launch_bounds__(256) void k_in_gemm(
    const float* __restrict__ x,
    const float* __restrict__ Ws, const float* __restrict__ bs,
    const float* __restrict__ Wd, const float* __restrict__ bd,
    const float* __restrict__ Wr,
    __bf16* __restrict__ fsb, __bf16* __restrict__ fdb, __bf16* __restrict__ resb,
    float* __restrict__ bnz)
{
    __shared__ float xl[8 * cIN];
    int tid = threadIdx.x;
    if (blockIdx.x == 0)
        for (int i = tid; i < 2 * cPART * cHID; i += 256) bnz[i] = 0.f;
    int rb  = blockIdx.x * 8;
    if (tid < 8 * cIN) xl[tid] = x[(size_t)rb * cIN + tid];
    __syncthreads();
    int j = tid;
    float ws[cIN], wd[cIN], wr[cIN];
#pragma unroll
    for (int k = 0; k < cIN; ++k) {
        ws[k] = Ws[k * cHID + j];
        wd[k] = Wd[k * cHID + j];
        wr[k] = Wr[k * cHID + j];
    }
    float vbs = bs[j], vbd = bd[j];
    for (int r = 0; r < 8; ++r) {
        float as = vbs, ad = vbd, ar = 0.f;
#pragma unroll
        for (int k = 0; k < cIN; ++k) {
            float xv = xl[r * cIN + k];
            as += xv * ws[k];
            ad += xv * wd[k];
            ar += xv * wr[k];
        }
        size_t o = (size_t)(rb + r) * cHID + j;
        fsb[o] = (__bf16)as; fdb[o] = (__bf16)ad; resb[o] = (__bf16)ar;
    }
}

// ---- weight convert + transpose into per-layer Wcat[512][256] ----
__global__ __launch_bounds__(256) void k_wcvt(
    const float* __restrict__ Ws_r, const float* __restrict__ Wd_r,
    __bf16* __restrict__ WT)
{
    int mat = blockIdx.y;
    int l = mat >> 1;
    const float* W = ((mat & 1) ? Wd_r : Ws_r) + (size_t)l * cHID * cHID;
    __bf16* T = WT + (size_t)l * 512 * cHID + (size_t)(mat & 1) * cHID * cHID;
    int k = blockIdx.x, n = threadIdx.x;
    T[(size_t)n * cHID + k] = (__bf16)W[(size_t)k * cHID + n];
}

// ---- layers 1-3: 128x128-tile LDS-staged MFMA GEMM (m97 pattern) ----
// block (0,0) zeroes BN partial accumulators for this layer
__global__ __launch_bounds__(256) void k_gemm_mfma(
    const __bf16* __restrict__ hb, const __bf16* __restrict__ Wcat,
    const float* __restrict__ bs, const float* __restrict__ bd,
    __bf16* __restrict__ fsb, __bf16* __restrict__ fdb,
    float* __restrict__ bnz)
{
    __shared__ __bf16 lA[128 * 32];   // 8 KB
    __shared__ __bf16 lB[128 * 32];   // 8 KB
    int tid = threadIdx.x, lane = tid & 63, w = tid >> 6;
    if (blockIdx.x == 0 && blockIdx.y == 0)
        for (int i = tid; i < 2 * cPART * cHID; i += 256) bnz[i] = 0.f;
    int wr = w >> 1, wc = w & 1;
    int rc = lane & 15, kg = lane >> 4;
    int m0  = blockIdx.x * 128;
    int bn0 = blockIdx.y * 128;

    f32x4 acc[4][4];
#pragma unroll
    for (int m = 0; m < 4; ++m)
#pragma unroll
        for (int n = 0; n < 4; ++n)
            acc[m][n] = (f32x4){0.f, 0.f, 0.f, 0.f};

#pragma unroll 1
    for (int ks = 0; ks < 8; ++ks) {
        int k0 = ks * 32;
#pragma unroll
        for (int j = 0; j < 2; ++j) {
            int c   = j * 256 + tid;
            int row = c >> 2, ci = c & 3;
            __bf16* dA = &lA[(size_t)(j * 256 + w * 64) * 8];
            __bf16* dB = &lB[(size_t)(j * 256 + w * 64) * 8];
            gl_lds16(hb   + (size_t)(m0  + row) * cHID + k0 + ci * 8, dA);
            gl_lds16(Wcat + (size_t)(bn0 + row) * cHID + k0 + ci * 8, dB);
        }
        __syncthreads();

        bf16x8 a[4], b[4];
#pragma unroll
        for (int m = 0; m < 4; ++m)
            a[m] = *(const bf16x8*)&lA[(wr * 64 + m * 16 + rc) * 32 + kg * 8];
#pragma unroll
        for (int n = 0; n < 4; ++n)
            b[n] = *(const bf16x8*)&lB[(wc * 64 + n * 16 + rc) * 32 + kg * 8];
#pragma unroll
        for (int m = 0; m < 4; ++m)
#pragma unroll
            for (int n = 0; n < 4; ++n)
                acc[m][n] = __builtin_amdgcn_mfma_f32_16x16x32_bf16(a[m], b[n], acc[m][n], 0, 0, 0);
        __syncthreads();
    }

#pragma unroll
    for (int m = 0; m < 4; ++m) {
        int rbase = m0 + wr * 64 + m * 16 + kg * 4;
#pragma unroll
        for (int n = 0; n < 4; ++n) {
            int col = bn0 + wc * 64 + n * 16 + rc;
            bool isS = col < cHID;
            int  cc  = isS ? col : col - cHID;
            float bias = isS ? bs[cc] : bd[cc];
            __bf16* dst = isS ? fsb : fdb;
#pragma unroll
            for (int i = 0; i < 4; ++i) {
                int r = rbase + i;
                if (r < cN)
                    dst[(size_t)r * cHID + cc] = (__bf16)(acc[m][n][i] + bias);
            }
        }
    }
}

// ---- CSR build by dst: chunked stable counting sort (deterministic) ----
__global__ __launch_bounds__(256) void k_csr(
    const int* __restrict__ dst, int* __restrict__ csr,
    int* __restrict__ off, int* __restrict__ deg)
{
    __shared__ int dstl[cEPG];
    __shared__ int cnt[cCH * 128];
    __shared__ int offl[cNPG];
    __shared__ int tot[128];
    int g = blockIdx.x, tid = threadIdx.x;
    int nb = g * cNPG, eb = g * cEPG;

    for (int i = tid; i < cEPG; i += 256) dstl[i] = dst[eb + i] - nb;
    for (int i = tid; i < cCH * 128; i += 256) cnt[i] = 0;
    __syncthreads();

    for (int i = tid; i < cEPG; i += 256)
        atomicAdd(&cnt[(i / cCHS) * 128 + dstl[i]], 1);
    __syncthreads();

    int mytot = 0;
    if (tid < cNPG) {
        int run = 0;
        for (int c = 0; c < cCH; ++c) {
            int t = cnt[c * 128 + tid];
            cnt[c * 128 + tid] = run;
            run += t;
        }
        mytot = run;
    }
    if (tid < 128) tot[tid] = (tid < cNPG) ? mytot : 0;
    __syncthreads();
    for (int ofs = 1; ofs < 128; ofs <<= 1) {
        int t = 0;
        if (tid < 128 && tid >= ofs) t = tot[tid - ofs];
        __syncthreads();
        if (tid < 128) tot[tid] += t;
        __syncthreads();
    }
    if (tid < cNPG) {
        int excl = tot[tid] - mytot;
        offl[tid] = excl;
        off[nb + tid] = eb + excl;
        deg[nb + tid] = mytot;
    }
    __syncthreads();

    if (tid < cCH) {
        for (int j = 0; j < cCHS; ++j) {
            int i = tid * cCHS + j;
            int n = dstl[i];
            int k = cnt[tid * 128 + n]++;
            csr[eb + offl[n] + k] = eb + i;
        }
    }
}

// ---- fused edge stage: wave/node single pass + hierarchical BN stats ----
// blockIdx swizzle: g = bid % 200 keeps each graph's blocks on one XCD
__global__ __launch_bounds__(256) void k_edge2(
    const __bf16* __restrict__ fsb, const __bf16* __restrict__ fdb,
    const __bf16* __restrict__ resb, const float* __restrict__ avec,
    const int* __restrict__ csr, const int* __restrict__ off,
    const int* __restrict__ deg, const int* __restrict__ src,
    float* __restrict__ hpre, float* __restrict__ attn_out,
    float* __restrict__ spill, float* __restrict__ psum,
    float* __restrict__ pssq, float* __restrict__ fcl)
{
    __shared__ int   sidx[4][64];
    __shared__ int   eidx[4][64];
    __shared__ float exbuf[4][64];
    __shared__ float hblk[4][256];
    int tid = threadIdx.x, lane = tid & 63, w = tid >> 6;
    int bid = blockIdx.x;
    if (bid < cG)                              // zero this layer's featcat row
        fcl[(size_t)bid * (4 * cHID) + tid] = 0.f;
    int g   = bid % cG;                         // 5000 blocks = 200 graphs x 25
    int nid = g * cNPG + (bid / cG) * 4 + w;
    int dg = deg[nid], base = off[nid];

    for (int i = lane; i < dg && i < 64; i += 64) {
        int e = csr[base + i];
        eidx[w][i] = e;
        sidx[w][i] = src[e];
    }

    float4 a4  = *(const float4*)(avec + lane * 4);
    float4 fd4 = cvt4(*(const bf16x4*)(fdb + (size_t)nid * cHID + lane * 4));
    float4 r4  = cvt4(*(const bf16x4*)(resb + (size_t)nid * cHID + lane * 4));

    // single pass: score -> exp -> accumulate (fs slice reused in registers)
    float den = 0.f;
    float4 acc = {0.f, 0.f, 0.f, 0.f};
    for (int i = 0; i < dg; ++i) {
        int s = (i < 64) ? sidx[w][i] : src[csr[base + i]];
        float4 f4 = cvt4(*(const bf16x4*)(fsb + (size_t)s * cHID + lane * 4));
        float v0 = f4.x + fd4.x, v1 = f4.y + fd4.y;
        float v2 = f4.z + fd4.z, v3 = f4.w + fd4.w;
        v0 = v0 > 0.f ? v0 : cSLOPE * v0;
        v1 = v1 > 0.f ? v1 : cSLOPE * v1;
        v2 = v2 > 0.f ? v2 : cSLOPE * v2;
        v3 = v3 > 0.f ? v3 : cSLOPE * v3;
        float part = v0 * a4.x + v1 * a4.y + v2 * a4.z + v3 * a4.w;
#pragma unroll
        for (int o = 32; o; o >>= 1) part += __shfl_xor(part, o);
        float ex = __expf(part);                // all lanes hold full score
        den += ex;
        acc.x += ex * f4.x; acc.y += ex * f4.y;
        acc.z += ex * f4.z; acc.w += ex * f4.w;
        if (lane == 0) {
            if (i < 64) exbuf[w][i] = ex;
            else        spill[csr[base + i]] = ex;
        }
    }
    float inv = (dg > 0) ? 1.f / den : 0.f;     // den identical on all lanes

    // attn output
    for (int i = lane; i < dg; i += 64) {
        float ex = (i < 64) ? exbuf[w][i] : spill[csr[base + i]];
        int e    = (i < 64) ? eidx[w][i]  : csr[base + i];
        attn_out[(size_t)e * 4] = ex * inv;
    }

    // normalize + residual; stash row in LDS for the stats reduce
    float4 o4 = {acc.x * inv + r4.x, acc.y * inv + r4.y,
                 acc.z * inv + r4.z, acc.w * inv + r4.w};
    *(float4*)(hpre + (size_t)nid * cHID + lane * 4) = o4;
    *(float4*)&hblk[w][lane * 4] = o4;
    __syncthreads();

    // hierarchical BN stats: block partial -> slot (bid & 31); ~156-way contention
    float v0 = hblk[0][tid], v1 = hblk[1][tid], v2 = hblk[2][tid], v3 = hblk[3][tid];
    int slot = (bid & (cPART - 1)) * cHID + tid;
    atomicAdd(&psum[slot], v0 + v1 + v2 + v3);
    atomicAdd(&pssq[slot], v0 * v0 + v1 * v1 + v2 * v2 + v3 * v3);
}

// ---- BN apply + ReLU + graph-mean (atomic): grid (200,4); bf16 h only ----
// sums the cPART partial slots to get the full column stats
__global__ __launch_bounds__(256) void k_bn_apply(
    const float* __restrict__ hpre,
    const float* __restrict__ psum, const float* __restrict__ pssq,
    const float* __restrict__ gamma, const float* __restrict__ beta,
    __bf16* __restrict__ hb, float* __restrict__ featcat_l)
{
    int j = threadIdx.x, g = blockIdx.x, q = blockIdx.y;
    float s = 0.f, qq = 0.f;
#pragma unroll
    for (int k = 0; k < cPART; ++k) {
        s  += psum[k * cHID + j];
        qq += pssq[k * cHID + j];
    }
    float mu  = s * (1.f / cN);
    float var = qq * (1.f / cN) - mu * mu;
    float sc  = gamma[j] * rsqrtf(var + cEPS);
    float sh  = beta[j] - mu * sc;
    float fsum = 0.f;
    int r0 = g * cNPG + q * 25;
    for (int r = 0; r < 25; ++r) {
        size_t i = (size_t)(r0 + r) * cHID + j;
        float v = hpre[i] * sc + sh;
        v = v > 0.f ? v : 0.f;
        hb[i] = (__bf16)v;
        fsum += v;
    }
    atomicAdd(&featcat_l[(size_t)g * (4 * cHID) + j], fsum * (1.f / cNPG));
}

// ---- head: feat2 = featcat @ fc1_W + fc1_b ----
__global__ __launch_bounds__(256) void k_fc1(
    const float* __restrict__ featcat, const float* __restrict__ W,
    const float* __restrict__ b, float* __restrict__ out)
{
    __shared__ float row[4 * cHID];
    int g = blockIdx.x, j = threadIdx.x;
    for (int i = j; i < 4 * cHID; i += 256) row[i] = featcat[(size_t)g * (4 * cHID) + i];
    __syncthreads();
    float acc = b[j];
    for (int k = 0; k < 4 * cHID; ++k) acc += row[k] * W[(size_t)k * cHID + j];
    out[(size_t)g * cHID + j] = acc;
}

// ---- head BN (over 200 rows) + ReLU, in place ----
__global__ __launch_bounds__(256) void k_fc_bn(
    float* __restrict__ f2, const float* __restrict__ gamma, const float* __restrict__ beta)
{
    int j = threadIdx.x;
    float s = 0.f, q = 0.f;
    for (int r = 0; r < cG; ++r) { float v = f2[(size_t)r * cHID + j]; s += v; q += v * v; }
    float mu  = s * (1.f / cG);
    float var = q * (1.f / cG) - mu * mu;
    float sc  = gamma[j] * rsqrtf(var + cEPS);
    float sh  = beta[j] - mu * sc;
    for (int r = 0; r < cG; ++r) {
        float v = f2[(size_t)r * cHID + j] * sc + sh;
        f2[(size_t)r * cHID + j] = v > 0.f ? v : 0.f;
    }
}

// ---- head: out[r*5+o] = feat2[r] . fc2_W[:,o] + fc2_b[o] ----
__global__ __launch_bounds__(256) void k_fc2(
    const float* __restrict__ f2, const float* __restrict__ W,
    const float* __restrict__ b, float* __restrict__ out)
{
    int t = blockIdx.x * 256 + threadIdx.x;
    if (t >= cG * 5) return;
    int r = t / 5, o = t % 5;
    float acc = b[o];
    for (int k = 0; k < cHID; ++k) acc += f2[(size_t)r * cHID + k] * W[k * 5 + o];
    out[t] = acc;
}

extern "C" void kernel_launch(void* const* d_in, const int* in_sizes, int n_in,
                              void* d_out, int out_size, void* d_ws, size_t ws_size,
                              hipStream_t stream)
{
    (void)in_sizes; (void)n_in; (void)out_size; (void)ws_size;
    const float* x     = (const float*)d_in[0];
    const float* Ws0   = (const float*)d_in[1];
    const float* bs0   = (const float*)d_in[2];
    const float* Wd0   = (const float*)d_in[3];
    const float* bd0   = (const float*)d_in[4];
    const float* a0    = (const float*)d_in[5];
    const float* Wres0 = (const float*)d_in[6];
    const float* g0    = (const float*)d_in[7];
    const float* be0   = (const float*)d_in[8];
    const float* Ws_r  = (const float*)d_in[9];
    const float* bs_r  = (const float*)d_in[10];
    const float* Wd_r  = (const float*)d_in[11];
    const float* bd_r  = (const float*)d_in[12];
    const float* a_r   = (const float*)d_in[13];
    const float* g_r   = (const float*)d_in[14];
    const float* be_r  = (const float*)d_in[15];
    const float* fc1_W = (const float*)d_in[16];
    const float* fc1_b = (const float*)d_in[17];
    const float* gfc   = (const float*)d_in[18];
    const float* bfc   = (const float*)d_in[19];
    const float* fc2_W = (const float*)d_in[20];
    const float* fc2_b = (const float*)d_in[21];
    const int*   src   = (const int*)d_in[22];
    const int*   dst   = (const int*)d_in[23];
    float* out = (float*)d_out;

    char* p = (char*)d_ws;
    float* hpre    = (float*)p; p += (size_t)cN * cHID * 4;
    float* featcat = (float*)p; p += (size_t)cG * 4 * cHID * 4;
    float* feat2   = (float*)p; p += (size_t)cG * cHID * 4;
    float* psum    = (float*)p; p += (size_t)cPART * cHID * 4;
    float* pssq    = (float*)p; p += (size_t)cPART * cHID * 4;
    float* spill   = (float*)p; p += (size_t)cE * 4;
    int*   csr     = (int*)p;   p += (size_t)cE * 4;
    int*   offv    = (int*)p;   p += (size_t)cN * 4;
    int*   degv    = (int*)p;   p += (size_t)cN * 4;
    __bf16* hb     = (__bf16*)p; p += (size_t)cN * cHID * 2;
    __bf16* resb0  = (__bf16*)p; p += (size_t)cN * cHID * 2;
    __bf16* fsb    = (__bf16*)p; p += (size_t)cN * cHID * 2;
    __bf16* fdb    = (__bf16*)p; p += (size_t)cN * cHID * 2;
    __bf16* WT     = (__bf16*)p; p += (size_t)3 * 512 * cHID * 2;

    // one-time setup: weight convert/transpose + CSR by dst
    k_wcvt<<<dim3(cHID, 6), 256, 0, stream>>>(Ws_r, Wd_r, WT);
    k_csr<<<cG, 256, 0, stream>>>(dst, csr, offv, degv);

    // layer 0 projections (f32 math, bf16 emit); zeroes BN partials
    k_in_gemm<<<cN / 8, 256, 0, stream>>>(x, Ws0, bs0, Wd0, bd0, Wres0,
                                          fsb, fdb, resb0, psum);

    for (int l = 0; l < 4; ++l) {
        if (l > 0) {
            k_gemm_mfma<<<dim3(157, 4), 256, 0, stream>>>(
                hb,
                WT + (size_t)(l - 1) * 512 * cHID,
                bs_r + (size_t)(l - 1) * cHID, bd_r + (size_t)(l - 1) * cHID,
                fsb, fdb, psum);
        }
        const float* ap = (l == 0) ? a0 : a_r + (size_t)(l - 1) * cHID;
        const __bf16* rb = (l == 0) ? resb0 : hb;
        float* fcl = featcat + (size_t)l * cHID;
        k_edge2<<<cN / 4, 256, 0, stream>>>(fsb, fdb, rb, ap, csr, offv, degv, src,
                                            hpre, out + 1000 + l, spill,
                                            psum, pssq, fcl);
        const float* gm = (l == 0) ? g0  : g_r  + (size_t)(l - 1) * cHID;
        const float* bt = (l == 0) ? be0 : be_r + (size_t)(l - 1) * cHID;
        k_bn_apply<<<dim3(cG, 4), 256, 0, stream>>>(hpre, psum, pssq, gm, bt, hb, fcl);
    }

    k_fc1<<<cG, 256, 0, stream>>>(featcat, fc1_W, fc1_b, feat2);
    k_fc_bn<<<1, 256, 0, stream>>>(feat2, gfc, bfc);
    k_fc2<<<4, 256, 0, stream>>>(feat2, fc2_W, fc2_b, out);
}

// Round 16
// 288.385 us; speedup vs baseline: 2.4334x; 1.0765x over previous
//
#include <hip/hip_runtime.h>

typedef __bf16 bf16x8 __attribute__((ext_vector_type(8)));
typedef __bf16 bf16x4 __attribute__((ext_vector_type(4)));
typedef float f32x4 __attribute__((ext_vector_type(4)));

constexpr int cN   = 20000;   // nodes total
constexpr int cG   = 200;     // graphs
constexpr int cNPG = 100;     // nodes per graph
constexpr int cE   = 160000;  // edges total
constexpr int cEPG = 800;     // edges per graph
constexpr int cHID = 256;
constexpr int cIN  = 21;
constexpr float cEPS   = 1e-5f;
constexpr float cSLOPE = 0.2f;
constexpr int cCH  = 32;      // csr chunks per graph
constexpr int cCHS = 25;      // edges per chunk
constexpr int cPART = 32;     // BN-stat partial slots (contention 5000 -> 156)

__device__ __forceinline__ float4 cvt4(bf16x4 v) {
    return make_float4((float)v.x, (float)v.y, (float)v.z, (float)v.w);
}
__device__ __forceinline__ bf16x4 tobf4(float4 v) {
    bf16x4 r;
    r.x = (__bf16)v.x; r.y = (__bf16)v.y; r.z = (__bf16)v.z; r.w = (__bf16)v.w;
    return r;
}

// async global->LDS, 16B per lane; lds dest must be wave-uniform base
__device__ __forceinline__ void gl_lds16(const __bf16* g, __bf16* l) {
    __builtin_amdgcn_global_load_lds(
        (const __attribute__((address_space(1))) void*)g,
        (__attribute__((address_space(3))) void*)l, 16, 0, 0);
}

// ---- layer-0: fsb/fdb = bf16(x@W+b), resb = bf16(x@Wres) ----
// block 0 zeroes the 2*cPART*256 BN partial accumulators
__global__ __launch_bounds__(256) void k_in_gemm(
    const float* __restrict__ x,
    const float* __restrict__ Ws, const float* __restrict__ bs,
    const float* __restrict__ Wd, const float* __restrict__ bd,
    const float* __restrict__ Wr,
    __bf16* __restrict__ fsb, __bf16* __restrict__ fdb, __bf16* __restrict__ resb,
    float* __restrict__ bnz)
{
    __shared__ float xl[8 * cIN];
    int tid = threadIdx.x;
    if (blockIdx.x == 0)
        for (int i = tid; i < 2 * cPART * cHID; i += 256) bnz[i] = 0.f;
    int rb  = blockIdx.x * 8;
    if (tid < 8 * cIN) xl[tid] = x[(size_t)rb * cIN + tid];
    __syncthreads();
    int j = tid;
    float ws[cIN], wd[cIN], wr[cIN];
#pragma unroll
    for (int k = 0; k < cIN; ++k) {
        ws[k] = Ws[k * cHID + j];
        wd[k] = Wd[k * cHID + j];
        wr[k] = Wr[k * cHID + j];
    }
    float vbs = bs[j], vbd = bd[j];
    for (int r = 0; r < 8; ++r) {
        float as = vbs, ad = vbd, ar = 0.f;
#pragma unroll
        for (int k = 0; k < cIN; ++k) {
            float xv = xl[r * cIN + k];
            as += xv * ws[k];
            ad += xv * wd[k];
            ar += xv * wr[k];
        }
        size_t o = (size_t)(rb + r) * cHID + j;
        fsb[o] = (__bf16)as; fdb[o] = (__bf16)ad; resb[o] = (__bf16)ar;
    }
}

// ---- weight convert + transpose into per-layer Wcat[512][256] ----
__global__ __launch_bounds__(256) void k_wcvt(
    const float* __restrict__ Ws_r, const float* __restrict__ Wd_r,
    __bf16* __restrict__ WT)
{
    int mat = blockIdx.y;
    int l = mat >> 1;
    const float* W = ((mat & 1) ? Wd_r : Ws_r) + (size_t)l * cHID * cHID;
    __bf16* T = WT + (size_t)l * 512 * cHID + (size_t)(mat & 1) * cHID * cHID;
    int k = blockIdx.x, n = threadIdx.x;
    T[(size_t)n * cHID + k] = (__bf16)W[(size_t)k * cHID + n];
}

// ---- layers 1-3: 128x128-tile LDS-staged MFMA GEMM (m97 pattern) ----
// block (0,0) zeroes BN partial accumulators for this layer
__global__ __launch_bounds__(256) void k_gemm_mfma(
    const __bf16* __restrict__ hb, const __bf16* __restrict__ Wcat,
    const float* __restrict__ bs, const float* __restrict__ bd,
    __bf16* __restrict__ fsb, __bf16* __restrict__ fdb,
    float* __restrict__ bnz)
{
    __shared__ __bf16 lA[128 * 32];   // 8 KB
    __shared__ __bf16 lB[128 * 32];   // 8 KB
    int tid = threadIdx.x, lane = tid & 63, w = tid >> 6;
    if (blockIdx.x == 0 && blockIdx.y == 0)
        for (int i = tid; i < 2 * cPART * cHID; i += 256) bnz[i] = 0.f;
    int wr = w >> 1, wc = w & 1;
    int rc = lane & 15, kg = lane >> 4;
    int m0  = blockIdx.x * 128;
    int bn0 = blockIdx.y * 128;

    f32x4 acc[4][4];
#pragma unroll
    for (int m = 0; m < 4; ++m)
#pragma unroll
        for (int n = 0; n < 4; ++n)
            acc[m][n] = (f32x4){0.f, 0.f, 0.f, 0.f};

#pragma unroll 1
    for (int ks = 0; ks < 8; ++ks) {
        int k0 = ks * 32;
#pragma unroll
        for (int j = 0; j < 2; ++j) {
            int c   = j * 256 + tid;
            int row = c >> 2, ci = c & 3;
            __bf16* dA = &lA[(size_t)(j * 256 + w * 64) * 8];
            __bf16* dB = &lB[(size_t)(j * 256 + w * 64) * 8];
            gl_lds16(hb   + (size_t)(m0  + row) * cHID + k0 + ci * 8, dA);
            gl_lds16(Wcat + (size_t)(bn0 + row) * cHID + k0 + ci * 8, dB);
        }
        __syncthreads();

        bf16x8 a[4], b[4];
#pragma unroll
        for (int m = 0; m < 4; ++m)
            a[m] = *(const bf16x8*)&lA[(wr * 64 + m * 16 + rc) * 32 + kg * 8];
#pragma unroll
        for (int n = 0; n < 4; ++n)
            b[n] = *(const bf16x8*)&lB[(wc * 64 + n * 16 + rc) * 32 + kg * 8];
#pragma unroll
        for (int m = 0; m < 4; ++m)
#pragma unroll
            for (int n = 0; n < 4; ++n)
                acc[m][n] = __builtin_amdgcn_mfma_f32_16x16x32_bf16(a[m], b[n], acc[m][n], 0, 0, 0);
        __syncthreads();
    }

#pragma unroll
    for (int m = 0; m < 4; ++m) {
        int rbase = m0 + wr * 64 + m * 16 + kg * 4;
#pragma unroll
        for (int n = 0; n < 4; ++n) {
            int col = bn0 + wc * 64 + n * 16 + rc;
            bool isS = col < cHID;
            int  cc  = isS ? col : col - cHID;
            float bias = isS ? bs[cc] : bd[cc];
            __bf16* dst = isS ? fsb : fdb;
#pragma unroll
            for (int i = 0; i < 4; ++i) {
                int r = rbase + i;
                if (r < cN)
                    dst[(size_t)r * cHID + cc] = (__bf16)(acc[m][n][i] + bias);
            }
        }
    }
}

// ---- CSR build by dst: chunked stable counting sort (deterministic) ----
__global__ __launch_bounds__(256) void k_csr(
    const int* __restrict__ dst, int* __restrict__ csr,
    int* __restrict__ off, int* __restrict__ deg)
{
    __shared__ int dstl[cEPG];
    __shared__ int cnt[cCH * 128];
    __shared__ int offl[cNPG];
    __shared__ int tot[128];
    int g = blockIdx.x, tid = threadIdx.x;
    int nb = g * cNPG, eb = g * cEPG;

    for (int i = tid; i < cEPG; i += 256) dstl[i] = dst[eb + i] - nb;
    for (int i = tid; i < cCH * 128; i += 256) cnt[i] = 0;
    __syncthreads();

    for (int i = tid; i < cEPG; i += 256)
        atomicAdd(&cnt[(i / cCHS) * 128 + dstl[i]], 1);
    __syncthreads();

    int mytot = 0;
    if (tid < cNPG) {
        int run = 0;
        for (int c = 0; c < cCH; ++c) {
            int t = cnt[c * 128 + tid];
            cnt[c * 128 + tid] = run;
            run += t;
        }
        mytot = run;
    }
    if (tid < 128) tot[tid] = (tid < cNPG) ? mytot : 0;
    __syncthreads();
    for (int ofs = 1; ofs < 128; ofs <<= 1) {
        int t = 0;
        if (tid < 128 && tid >= ofs) t = tot[tid - ofs];
        __syncthreads();
        if (tid < 128) tot[tid] += t;
        __syncthreads();
    }
    if (tid < cNPG) {
        int excl = tot[tid] - mytot;
        offl[tid] = excl;
        off[nb + tid] = eb + excl;
        deg[nb + tid] = mytot;
    }
    __syncthreads();

    if (tid < cCH) {
        for (int j = 0; j < cCHS; ++j) {
            int i = tid * cCHS + j;
            int n = dstl[i];
            int k = cnt[tid * 128 + n]++;
            csr[eb + offl[n] + k] = eb + i;
        }
    }
}

// ---- fused edge stage: wave/node single pass, depth-2 gather pipeline ----
// blockIdx swizzle: g = bid % 200 keeps each graph's blocks on one XCD
__global__ __launch_bounds__(256) void k_edge2(
    const __bf16* __restrict__ fsb, const __bf16* __restrict__ fdb,
    const __bf16* __restrict__ resb, const float* __restrict__ avec,
    const int* __restrict__ csr, const int* __restrict__ off,
    const int* __restrict__ deg, const int* __restrict__ src,
    __bf16* __restrict__ hpb, float* __restrict__ attn_out,
    float* __restrict__ spill, float* __restrict__ psum,
    float* __restrict__ pssq, float* __restrict__ fcl)
{
    __shared__ int   sidx[4][64];
    __shared__ int   eidx[4][64];
    __shared__ float exbuf[4][64];
    __shared__ float hblk[4][256];
    int tid = threadIdx.x, lane = tid & 63, w = tid >> 6;
    int bid = blockIdx.x;
    if (bid < cG)                              // zero this layer's featcat row
        fcl[(size_t)bid * (4 * cHID) + tid] = 0.f;
    int g   = bid % cG;                         // 5000 blocks = 200 graphs x 25
    int nid = g * cNPG + (bid / cG) * 4 + w;
    int dg = deg[nid], base = off[nid];

    for (int i = lane; i < dg && i < 64; i += 64) {
        int e = csr[base + i];
        eidx[w][i] = e;
        sidx[w][i] = src[e];
    }

    float4 a4  = *(const float4*)(avec + lane * 4);
    float4 fd4 = cvt4(*(const bf16x4*)(fdb + (size_t)nid * cHID + lane * 4));
    float4 r4  = cvt4(*(const bf16x4*)(resb + (size_t)nid * cHID + lane * 4));
    const __bf16* fsl = fsb + lane * 4;

    // depth-2 software pipeline: gather i+2 issues before compute of i
    bf16x4 fA{}, fB{};
    if (dg > 0) fA = *(const bf16x4*)(fsl + (size_t)sidx[w][0] * cHID);
    if (dg > 1) fB = *(const bf16x4*)(fsl + (size_t)sidx[w][1] * cHID);

    float den = 0.f;
    float4 acc = {0.f, 0.f, 0.f, 0.f};
    for (int i = 0; i < dg; ++i) {
        float4 f4 = cvt4(fA);
        fA = fB;
        if (i + 2 < dg) {
            int s2 = (i + 2 < 64) ? sidx[w][i + 2] : src[csr[base + i + 2]];
            fB = *(const bf16x4*)(fsl + (size_t)s2 * cHID);
        }
        float v0 = f4.x + fd4.x, v1 = f4.y + fd4.y;
        float v2 = f4.z + fd4.z, v3 = f4.w + fd4.w;
        v0 = v0 > 0.f ? v0 : cSLOPE * v0;
        v1 = v1 > 0.f ? v1 : cSLOPE * v1;
        v2 = v2 > 0.f ? v2 : cSLOPE * v2;
        v3 = v3 > 0.f ? v3 : cSLOPE * v3;
        float part = v0 * a4.x + v1 * a4.y + v2 * a4.z + v3 * a4.w;
#pragma unroll
        for (int o = 32; o; o >>= 1) part += __shfl_xor(part, o);
        float ex = __expf(part);                // all lanes hold full score
        den += ex;
        acc.x += ex * f4.x; acc.y += ex * f4.y;
        acc.z += ex * f4.z; acc.w += ex * f4.w;
        if (lane == 0) {
            if (i < 64) exbuf[w][i] = ex;
            else        spill[csr[base + i]] = ex;
        }
    }
    float inv = (dg > 0) ? 1.f / den : 0.f;     // den identical on all lanes

    // attn output
    for (int i = lane; i < dg; i += 64) {
        float ex = (i < 64) ? exbuf[w][i] : spill[csr[base + i]];
        int e    = (i < 64) ? eidx[w][i]  : csr[base + i];
        attn_out[(size_t)e * 4] = ex * inv;
    }

    // normalize + residual; bf16 hpre out; f32 row stashed for stats
    float4 o4 = {acc.x * inv + r4.x, acc.y * inv + r4.y,
                 acc.z * inv + r4.z, acc.w * inv + r4.w};
    *(bf16x4*)(hpb + (size_t)nid * cHID + lane * 4) = tobf4(o4);
    *(float4*)&hblk[w][lane * 4] = o4;
    __syncthreads();

    // hierarchical BN stats: block partial -> slot (bid & 31); ~156-way contention
    float v0 = hblk[0][tid], v1 = hblk[1][tid], v2 = hblk[2][tid], v3 = hblk[3][tid];
    int slot = (bid & (cPART - 1)) * cHID + tid;
    atomicAdd(&psum[slot], v0 + v1 + v2 + v3);
    atomicAdd(&pssq[slot], v0 * v0 + v1 * v1 + v2 * v2 + v3 * v3);
}

// ---- BN apply + ReLU + graph-mean (atomic): grid (200,4); bf16 in/out ----
// sums the cPART partial slots to get the full column stats
__global__ __launch_bounds__(256) void k_bn_apply(
    const __bf16* __restrict__ hpb,
    const float* __restrict__ psum, const float* __restrict__ pssq,
    const float* __restrict__ gamma, const float* __restrict__ beta,
    __bf16* __restrict__ hb, float* __restrict__ featcat_l)
{
    int j = threadIdx.x, g = blockIdx.x, q = blockIdx.y;
    float s = 0.f, qq = 0.f;
#pragma unroll
    for (int k = 0; k < cPART; ++k) {
        s  += psum[k * cHID + j];
        qq += pssq[k * cHID + j];
    }
    float mu  = s * (1.f / cN);
    float var = qq * (1.f / cN) - mu * mu;
    float sc  = gamma[j] * rsqrtf(var + cEPS);
    float sh  = beta[j] - mu * sc;
    float fsum = 0.f;
    int r0 = g * cNPG + q * 25;
    for (int r = 0; r < 25; ++r) {
        size_t i = (size_t)(r0 + r) * cHID + j;
        float v = (float)hpb[i] * sc + sh;
        v = v > 0.f ? v : 0.f;
        hb[i] = (__bf16)v;
        fsum += v;
    }
    atomicAdd(&featcat_l[(size_t)g * (4 * cHID) + j], fsum * (1.f / cNPG));
}

// ---- head: feat2 = featcat @ fc1_W + fc1_b ----
__global__ __launch_bounds__(256) void k_fc1(
    const float* __restrict__ featcat, const float* __restrict__ W,
    const float* __restrict__ b, float* __restrict__ out)
{
    __shared__ float row[4 * cHID];
    int g = blockIdx.x, j = threadIdx.x;
    for (int i = j; i < 4 * cHID; i += 256) row[i] = featcat[(size_t)g * (4 * cHID) + i];
    __syncthreads();
    float acc = b[j];
    for (int k = 0; k < 4 * cHID; ++k) acc += row[k] * W[(size_t)k * cHID + j];
    out[(size_t)g * cHID + j] = acc;
}

// ---- head BN (over 200 rows) + ReLU, in place ----
__global__ __launch_bounds__(256) void k_fc_bn(
    float* __restrict__ f2, const float* __restrict__ gamma, const float* __restrict__ beta)
{
    int j = threadIdx.x;
    float s = 0.f, q = 0.f;
    for (int r = 0; r < cG; ++r) { float v = f2[(size_t)r * cHID + j]; s += v; q += v * v; }
    float mu  = s * (1.f / cG);
    float var = q * (1.f / cG) - mu * mu;
    float sc  = gamma[j] * rsqrtf(var + cEPS);
    float sh  = beta[j] - mu * sc;
    for (int r = 0; r < cG; ++r) {
        float v = f2[(size_t)r * cHID + j] * sc + sh;
        f2[(size_t)r * cHID + j] = v > 0.f ? v : 0.f;
    }
}

// ---- head: out[r*5+o] = feat2[r] . fc2_W[:,o] + fc2_b[o] ----
__global__ __launch_bounds__(256) void k_fc2(
    const float* __restrict__ f2, const float* __restrict__ W,
    const float* __restrict__ b, float* __restrict__ out)
{
    int t = blockIdx.x * 256 + threadIdx.x;
    if (t >= cG * 5) return;
    int r = t / 5, o = t % 5;
    float acc = b[o];
    for (int k = 0; k < cHID; ++k) acc += f2[(size_t)r * cHID + k] * W[k * 5 + o];
    out[t] = acc;
}

extern "C" void kernel_launch(void* const* d_in, const int* in_sizes, int n_in,
                              void* d_out, int out_size, void* d_ws, size_t ws_size,
                              hipStream_t stream)
{
    (void)in_sizes; (void)n_in; (void)out_size; (void)ws_size;
    const float* x     = (const float*)d_in[0];
    const float* Ws0   = (const float*)d_in[1];
    const float* bs0   = (const float*)d_in[2];
    const float* Wd0   = (const float*)d_in[3];
    const float* bd0   = (const float*)d_in[4];
    const float* a0    = (const float*)d_in[5];
    const float* Wres0 = (const float*)d_in[6];
    const float* g0    = (const float*)d_in[7];
    const float* be0   = (const float*)d_in[8];
    const float* Ws_r  = (const float*)d_in[9];
    const float* bs_r  = (const float*)d_in[10];
    const float* Wd_r  = (const float*)d_in[11];
    const float* bd_r  = (const float*)d_in[12];
    const float* a_r   = (const float*)d_in[13];
    const float* g_r   = (const float*)d_in[14];
    const float* be_r  = (const float*)d_in[15];
    const float* fc1_W = (const float*)d_in[16];
    const float* fc1_b = (const float*)d_in[17];
    const float* gfc   = (const float*)d_in[18];
    const float* bfc   = (const float*)d_in[19];
    const float* fc2_W = (const float*)d_in[20];
    const float* fc2_b = (const float*)d_in[21];
    const int*   src   = (const int*)d_in[22];
    const int*   dst   = (const int*)d_in[23];
    float* out = (float*)d_out;

    char* p = (char*)d_ws;
    float* featcat = (float*)p; p += (size_t)cG * 4 * cHID * 4;
    float* feat2   = (float*)p; p += (size_t)cG * cHID * 4;
    float* psum    = (float*)p; p += (size_t)cPART * cHID * 4;
    float* pssq    = (float*)p; p += (size_t)cPART * cHID * 4;
    float* spill   = (float*)p; p += (size_t)cE * 4;
    int*   csr     = (int*)p;   p += (size_t)cE * 4;
    int*   offv    = (int*)p;   p += (size_t)cN * 4;
    int*   degv    = (int*)p;   p += (size_t)cN * 4;
    __bf16* hpb    = (__bf16*)p; p += (size_t)cN * cHID * 2;
    __bf16* hb     = (__bf16*)p; p += (size_t)cN * cHID * 2;
    __bf16* resb0  = (__bf16*)p; p += (size_t)cN * cHID * 2;
    __bf16* fsb    = (__bf16*)p; p += (size_t)cN * cHID * 2;
    __bf16* fdb    = (__bf16*)p; p += (size_t)cN * cHID * 2;
    __bf16* WT     = (__bf16*)p; p += (size_t)3 * 512 * cHID * 2;

    // one-time setup: weight convert/transpose + CSR by dst
    k_wcvt<<<dim3(cHID, 6), 256, 0, stream>>>(Ws_r, Wd_r, WT);
    k_csr<<<cG, 256, 0, stream>>>(dst, csr, offv, degv);

    // layer 0 projections (f32 math, bf16 emit); zeroes BN partials
    k_in_gemm<<<cN / 8, 256, 0, stream>>>(x, Ws0, bs0, Wd0, bd0, Wres0,
                                          fsb, fdb, resb0, psum);

    for (int l = 0; l < 4; ++l) {
        if (l > 0) {
            k_gemm_mfma<<<dim3(157, 4), 256, 0, stream>>>(
                hb,
                WT + (size_t)(l - 1) * 512 * cHID,
                bs_r + (size_t)(l - 1) * cHID, bd_r + (size_t)(l - 1) * cHID,
                fsb, fdb, psum);
        }
        const float* ap = (l == 0) ? a0 : a_r + (size_t)(l - 1) * cHID;
        const __bf16* rb = (l == 0) ? resb0 : hb;
        float* fcl = featcat + (size_t)l * cHID;
        k_edge2<<<cN / 4, 256, 0, stream>>>(fsb, fdb, rb, ap, csr, offv, degv, src,
                                            hpb, out + 1000 + l, spill,
                                            psum, pssq, fcl);
        const float* gm = (l == 0) ? g0  : g_r  + (size_t)(l - 1) * cHID;
        const float* bt = (l == 0) ? be0 : be_r + (size_t)(l - 1) * cHID;
        k_bn_apply<<<dim3(cG, 4), 256, 0, stream>>>(hpb, psum, pssq, gm, bt, hb, fcl);
    }

    k_fc1<<<cG, 256, 0, stream>>>(featcat, fc1_W, fc1_b, feat2);
    k_fc_bn<<<1, 256, 0, stream>>>(feat2, gfc, bfc);
    k_fc2<<<4, 256, 0, stream>>>(feat2, fc2_W, fc2_b, out);
}